// Round 2
// baseline (611.945 us; speedup 1.0000x reference)
//
#include <hip/hip_runtime.h>
#include <math.h>

// Problem constants (fixed by the reference setup)
#define B_ 32
#define N_ 2048
#define D_ 64
#define R_ 32
#define T_ 31
#define O_ 12
#define HID_ 128
#define IN_DIM_ 63      // T_ + R_
#define NCH_ 8          // n-chunks for partial-U reduction
#define NC_ 64          // n rows per block in main kernel

// Workspace layout (float offsets)
#define OFF_QSP   0
#define OFF_PSP   (N_*R_)                        // 65536
#define OFF_UPART (OFF_PSP + N_*R_)              // 131072
#define OFF_U     (OFF_UPART + B_*NCH_*R_*D_)    // 655360
#define OFF_CTX   (OFF_U + B_*R_*D_)             // 720896
#define OFF_SUA   (OFF_CTX + B_*R_)              // 721920
// total floats = OFF_SUA + B_*O_*R_*D_ = 1,508,352  (~5.8 MB)

__device__ __forceinline__ float softplus_f(float x) {
    // logaddexp(x, 0) = max(x,0) + log1p(exp(-|x|))
    return fmaxf(x, 0.0f) + log1pf(expf(-fabsf(x)));
}
__device__ __forceinline__ float gelu_f(float x) {
    // exact gelu: 0.5*x*(1+erf(x/sqrt(2)))
    return 0.5f * x * (1.0f + erff(x * 0.70710678118654752440f));
}

// Kernel 1: softplus(Q_raw) -> Qsp, softplus(P_raw) -> Psp
__global__ __launch_bounds__(256) void k_softplus(const float* __restrict__ Qr,
                                                  const float* __restrict__ Pr,
                                                  float* __restrict__ ws) {
    int i = blockIdx.x * blockDim.x + threadIdx.x;
    if (i < N_ * R_) {
        ws[OFF_QSP + i] = softplus_f(Qr[i]);
    } else if (i < 2 * N_ * R_) {
        int j = i - N_ * R_;
        ws[OFF_PSP + j] = softplus_f(Pr[j]);
    }
}

// Kernel 2a: partial U over n-chunks. grid = B_*NCH_ blocks, 512 threads.
// thread: d = tid&63, rb = tid>>6 (wave-uniform), r in {rb, rb+8, rb+16, rb+24}
__global__ __launch_bounds__(512) void k_upart(const float* __restrict__ H,
                                               float* __restrict__ ws) {
    const float* __restrict__ Qsp = ws + OFF_QSP;
    float* __restrict__ Upart = ws + OFF_UPART;
    int b = blockIdx.x / NCH_;
    int c = blockIdx.x % NCH_;
    int tid = threadIdx.x;
    int d = tid & 63;
    int rb = __builtin_amdgcn_readfirstlane(tid >> 6);  // 0..7, wave-uniform
    float acc0 = 0.f, acc1 = 0.f, acc2 = 0.f, acc3 = 0.f;
    const int n0 = c * (N_ / NCH_);
    const float* __restrict__ Hb = H + (size_t)b * N_ * D_;
    for (int n = n0; n < n0 + N_ / NCH_; ++n) {
        float h = Hb[n * D_ + d];
        const float* q = Qsp + n * R_ + rb;   // uniform address -> s_load
        acc0 = fmaf(h, q[0],  acc0);
        acc1 = fmaf(h, q[8],  acc1);
        acc2 = fmaf(h, q[16], acc2);
        acc3 = fmaf(h, q[24], acc3);
    }
    float* up = Upart + ((size_t)(b * NCH_ + c) * R_) * D_ + d;
    up[(rb + 0) * D_]  = acc0;
    up[(rb + 8) * D_]  = acc1;
    up[(rb + 16) * D_] = acc2;
    up[(rb + 24) * D_] = acc3;
}

// Kernel 2b: reduce partials -> U, compute ctx = sqrt(mean_d U^2 + eps)
__global__ __launch_bounds__(512) void k_ured(float* __restrict__ ws) {
    const float* __restrict__ Upart = ws + OFF_UPART;
    float* __restrict__ U = ws + OFF_U;
    float* __restrict__ ctx = ws + OFF_CTX;
    int b = blockIdx.x;
    int tid = threadIdx.x;
    int d = tid & 63;
    int rb = tid >> 6;
    #pragma unroll
    for (int j = 0; j < 4; ++j) {
        int r = rb + 8 * j;
        float u = 0.f;
        #pragma unroll
        for (int c = 0; c < NCH_; ++c)
            u += Upart[((size_t)(b * NCH_ + c) * R_ + r) * D_ + d];
        U[((size_t)b * R_ + r) * D_ + d] = u;
        float sq = u * u;
        #pragma unroll
        for (int off = 32; off; off >>= 1) sq += __shfl_xor(sq, off, 64);
        if (d == 0) ctx[b * R_ + r] = sqrtf(sq * (1.0f / D_) + 1e-6f);
    }
}

// Kernel 3: per (b,o): feat -> gelu(feat@W1+b1) -> softplus(h@W2+b2)=s,
// then SUa[b,o,r,d] = a * s[r] * U[b,r,d].  grid = B_*O_, 128 threads.
__global__ __launch_bounds__(128) void k_mlp(const float* __restrict__ ts_out,
                                             const float* __restrict__ W1,
                                             const float* __restrict__ b1,
                                             const float* __restrict__ W2,
                                             const float* __restrict__ b2,
                                             const float* __restrict__ alpha,
                                             float* __restrict__ ws) {
    __shared__ float feat[IN_DIM_];
    __shared__ float hsh[HID_];
    __shared__ float ssh[R_];
    int bo = blockIdx.x;
    int b = bo / O_;
    int tid = threadIdx.x;
    const float* __restrict__ ctx = ws + OFF_CTX;
    if (tid < T_) feat[tid] = ts_out[(size_t)bo * T_ + tid];
    else if (tid < IN_DIM_) feat[tid] = ctx[b * R_ + (tid - T_)];
    __syncthreads();
    float acc = b1[tid];
    #pragma unroll 9
    for (int k = 0; k < IN_DIM_; ++k) acc = fmaf(feat[k], W1[k * HID_ + tid], acc);
    hsh[tid] = gelu_f(acc);
    __syncthreads();
    if (tid < R_) {
        float a2 = b2[tid];
        #pragma unroll 8
        for (int j = 0; j < HID_; ++j) a2 = fmaf(hsh[j], W2[j * R_ + tid], a2);
        ssh[tid] = softplus_f(a2);
    }
    __syncthreads();
    float a = fminf(fmaxf(alpha[0], 0.0f), 1.0f);
    const float* __restrict__ U = ws + OFF_U;
    float* __restrict__ SUa = ws + OFF_SUA;
    #pragma unroll
    for (int idx = tid; idx < R_ * D_; idx += 128) {
        int r = idx >> 6, d = idx & 63;
        SUa[((size_t)bo * R_ + r) * D_ + d] = a * ssh[r] * U[((size_t)b * R_ + r) * D_ + d];
    }
}

// Kernel 4: out[b,o,n,d] = (1-a)*H[b,n,d] + sum_r Psp[n,r]*SUa[b,o,r,d]
// grid = (N_/NC_, B_), block 256 (4 waves). lane=d; wave w owns o in {3w..3w+2};
// n is wave-uniform -> Psp row comes in via s_load (scalar operand to v_fmac).
// __launch_bounds__(256,4): cap VGPR<=128 so 4 blocks/CU (4 waves/SIMD) fit —
// su[3][32]=96 VGPR + temps was pushing past 128 -> 2 waves/SIMD, no latency hiding.
__global__ __launch_bounds__(256, 4) void k_main(const float* __restrict__ H,
                                                 const float* __restrict__ alpha,
                                                 const float* __restrict__ ws,
                                                 float* __restrict__ out) {
    const float* __restrict__ Psp = ws + OFF_PSP;
    const float* __restrict__ SUa = ws + OFF_SUA;
    int b = blockIdx.y;
    int nbase = blockIdx.x * NC_;
    int tid = threadIdx.x;
    int lane = tid & 63;
    int w = __builtin_amdgcn_readfirstlane(tid >> 6);  // 0..3
    float a = fminf(fmaxf(alpha[0], 0.0f), 1.0f);
    float oma = 1.0f - a;

    // Pre-load this wave's 3 o-slices of SUa: su[oi][r] (96 VGPRs)
    float su[3][R_];
    #pragma unroll
    for (int oi = 0; oi < 3; ++oi) {
        int o = w * 3 + oi;
        const float* sp = SUa + ((size_t)(b * O_ + o) * R_) * D_ + lane;
        #pragma unroll
        for (int r = 0; r < R_; ++r) su[oi][r] = sp[r * D_];
    }

    const float* __restrict__ Hb = H + ((size_t)b * N_ + nbase) * D_ + lane;
    const int o0 = w * 3;
    float* out0 = out + ((size_t)(b * O_ + o0) * N_ + nbase) * D_ + lane;

    #pragma unroll 2
    for (int ni = 0; ni < NC_; ++ni) {
        // Issue loads first: H value (vector) and P row (uniform -> SGPR).
        float hv = Hb[ni * D_];
        const float* pp = Psp + (size_t)(nbase + ni) * R_;
        float p[R_];
        #pragma unroll
        for (int r = 0; r < R_; ++r) p[r] = pp[r];
        float acc0 = oma * hv, acc1 = oma * hv, acc2 = oma * hv;
        #pragma unroll
        for (int r = 0; r < R_; ++r) {
            acc0 = fmaf(p[r], su[0][r], acc0);
            acc1 = fmaf(p[r], su[1][r], acc1);
            acc2 = fmaf(p[r], su[2][r], acc2);
        }
        out0[(size_t)0 * N_ * D_ + ni * D_] = acc0;
        out0[(size_t)1 * N_ * D_ + ni * D_] = acc1;
        out0[(size_t)2 * N_ * D_ + ni * D_] = acc2;
    }
}

extern "C" void kernel_launch(void* const* d_in, const int* in_sizes, int n_in,
                              void* d_out, int out_size, void* d_ws, size_t ws_size,
                              hipStream_t stream) {
    const float* H      = (const float*)d_in[0];
    const float* ts_out = (const float*)d_in[1];
    // d_in[2] is O (int scalar) — shapes are compile-time constants here
    const float* P_raw  = (const float*)d_in[3];
    const float* Q_raw  = (const float*)d_in[4];
    const float* W1     = (const float*)d_in[5];
    const float* b1     = (const float*)d_in[6];
    const float* W2     = (const float*)d_in[7];
    const float* b2     = (const float*)d_in[8];
    const float* alpha  = (const float*)d_in[9];
    float* out = (float*)d_out;
    float* ws  = (float*)d_ws;

    // 1. softplus of Q_raw and P_raw
    k_softplus<<<dim3((2 * N_ * R_ + 255) / 256), dim3(256), 0, stream>>>(Q_raw, P_raw, ws);
    // 2a. partial U
    k_upart<<<dim3(B_ * NCH_), dim3(512), 0, stream>>>(H, ws);
    // 2b. reduce U + ctx
    k_ured<<<dim3(B_), dim3(512), 0, stream>>>(ws);
    // 3. MLP -> s -> SUa
    k_mlp<<<dim3(B_ * O_), dim3(128), 0, stream>>>(ts_out, W1, b1, W2, b2, alpha, ws);
    // 4. main fused output
    k_main<<<dim3(N_ / NC_, B_), dim3(256), 0, stream>>>(H, alpha, ws, out);
}

// Round 3
// 112.998 us; speedup vs baseline: 5.4156x; 5.4156x over previous
//
#include <hip/hip_runtime.h>
#include <math.h>

// Problem constants (fixed by the reference setup)
#define B_ 32
#define N_ 2048
#define D_ 64
#define R_ 32
#define T_ 31
#define O_ 12
#define HID_ 128
#define IN_DIM_ 63      // T_ + R_
#define NCH_ 8          // n-chunks for partial-U reduction
#define NC_ 64          // n rows per block in main kernel

// Workspace layout (float offsets)
#define OFF_QSP   0
#define OFF_PSP   (N_*R_)                        // 65536
#define OFF_UPART (OFF_PSP + N_*R_)              // 131072
#define OFF_U     (OFF_UPART + B_*NCH_*R_*D_)    // 655360
#define OFF_CTX   (OFF_U + B_*R_*D_)             // 720896
#define OFF_SUA   (OFF_CTX + B_*R_)              // 721920
// total floats = OFF_SUA + B_*O_*R_*D_ = 1,508,352  (~5.8 MB)

__device__ __forceinline__ float softplus_f(float x) {
    // logaddexp(x, 0) = max(x,0) + log1p(exp(-|x|))
    return fmaxf(x, 0.0f) + log1pf(expf(-fabsf(x)));
}
__device__ __forceinline__ float gelu_f(float x) {
    // exact gelu: 0.5*x*(1+erf(x/sqrt(2)))
    return 0.5f * x * (1.0f + erff(x * 0.70710678118654752440f));
}

// Kernel 1: softplus(Q_raw) -> Qsp, softplus(P_raw) -> Psp
__global__ __launch_bounds__(256) void k_softplus(const float* __restrict__ Qr,
                                                  const float* __restrict__ Pr,
                                                  float* __restrict__ ws) {
    int i = blockIdx.x * blockDim.x + threadIdx.x;
    if (i < N_ * R_) {
        ws[OFF_QSP + i] = softplus_f(Qr[i]);
    } else if (i < 2 * N_ * R_) {
        int j = i - N_ * R_;
        ws[OFF_PSP + j] = softplus_f(Pr[j]);
    }
}

// Kernel 2a: partial U over n-chunks. grid = B_*NCH_ blocks, 512 threads.
// thread: d = tid&63, rb = tid>>6 (wave-uniform), r in {rb, rb+8, rb+16, rb+24}
__global__ __launch_bounds__(512) void k_upart(const float* __restrict__ H,
                                               float* __restrict__ ws) {
    const float* __restrict__ Qsp = ws + OFF_QSP;
    float* __restrict__ Upart = ws + OFF_UPART;
    int b = blockIdx.x / NCH_;
    int c = blockIdx.x % NCH_;
    int tid = threadIdx.x;
    int d = tid & 63;
    int rb = __builtin_amdgcn_readfirstlane(tid >> 6);  // 0..7, wave-uniform
    float acc0 = 0.f, acc1 = 0.f, acc2 = 0.f, acc3 = 0.f;
    const int n0 = c * (N_ / NCH_);
    const float* __restrict__ Hb = H + (size_t)b * N_ * D_;
    for (int n = n0; n < n0 + N_ / NCH_; ++n) {
        float h = Hb[n * D_ + d];
        const float* q = Qsp + n * R_ + rb;   // uniform address -> s_load
        acc0 = fmaf(h, q[0],  acc0);
        acc1 = fmaf(h, q[8],  acc1);
        acc2 = fmaf(h, q[16], acc2);
        acc3 = fmaf(h, q[24], acc3);
    }
    float* up = Upart + ((size_t)(b * NCH_ + c) * R_) * D_ + d;
    up[(rb + 0) * D_]  = acc0;
    up[(rb + 8) * D_]  = acc1;
    up[(rb + 16) * D_] = acc2;
    up[(rb + 24) * D_] = acc3;
}

// Kernel 2b: reduce partials -> U, compute ctx = sqrt(mean_d U^2 + eps)
__global__ __launch_bounds__(512) void k_ured(float* __restrict__ ws) {
    const float* __restrict__ Upart = ws + OFF_UPART;
    float* __restrict__ U = ws + OFF_U;
    float* __restrict__ ctx = ws + OFF_CTX;
    int b = blockIdx.x;
    int tid = threadIdx.x;
    int d = tid & 63;
    int rb = tid >> 6;
    #pragma unroll
    for (int j = 0; j < 4; ++j) {
        int r = rb + 8 * j;
        float u = 0.f;
        #pragma unroll
        for (int c = 0; c < NCH_; ++c)
            u += Upart[((size_t)(b * NCH_ + c) * R_ + r) * D_ + d];
        U[((size_t)b * R_ + r) * D_ + d] = u;
        float sq = u * u;
        #pragma unroll
        for (int off = 32; off; off >>= 1) sq += __shfl_xor(sq, off, 64);
        if (d == 0) ctx[b * R_ + r] = sqrtf(sq * (1.0f / D_) + 1e-6f);
    }
}

// Kernel 3: per (b,o): feat -> gelu(feat@W1+b1) -> softplus(h@W2+b2)=s,
// then SUa[b,o,r,d] = a * s[r] * U[b,r,d].  grid = B_*O_, 128 threads.
__global__ __launch_bounds__(128) void k_mlp(const float* __restrict__ ts_out,
                                             const float* __restrict__ W1,
                                             const float* __restrict__ b1,
                                             const float* __restrict__ W2,
                                             const float* __restrict__ b2,
                                             const float* __restrict__ alpha,
                                             float* __restrict__ ws) {
    __shared__ float feat[IN_DIM_];
    __shared__ float hsh[HID_];
    __shared__ float ssh[R_];
    int bo = blockIdx.x;
    int b = bo / O_;
    int tid = threadIdx.x;
    const float* __restrict__ ctx = ws + OFF_CTX;
    if (tid < T_) feat[tid] = ts_out[(size_t)bo * T_ + tid];
    else if (tid < IN_DIM_) feat[tid] = ctx[b * R_ + (tid - T_)];
    __syncthreads();
    float acc = b1[tid];
    #pragma unroll 9
    for (int k = 0; k < IN_DIM_; ++k) acc = fmaf(feat[k], W1[k * HID_ + tid], acc);
    hsh[tid] = gelu_f(acc);
    __syncthreads();
    if (tid < R_) {
        float a2 = b2[tid];
        #pragma unroll 8
        for (int j = 0; j < HID_; ++j) a2 = fmaf(hsh[j], W2[j * R_ + tid], a2);
        ssh[tid] = softplus_f(a2);
    }
    __syncthreads();
    float a = fminf(fmaxf(alpha[0], 0.0f), 1.0f);
    const float* __restrict__ U = ws + OFF_U;
    float* __restrict__ SUa = ws + OFF_SUA;
    #pragma unroll
    for (int idx = tid; idx < R_ * D_; idx += 128) {
        int r = idx >> 6, d = idx & 63;
        SUa[((size_t)bo * R_ + r) * D_ + d] = a * ssh[r] * U[((size_t)b * R_ + r) * D_ + d];
    }
}

// Kernel 4: out[b,o,n,d] = (1-a)*H[b,n,d] + sum_r Psp[n,r]*SUa[b,o,r,d]
// v3: ONE o per wave -> su[32] = 32 VGPR, total ~60 VGPR -> 8 waves/SIMD.
// No launch_bounds register cap (R2 lesson: capping below the live set spills
// to scratch -> 1.45 GB FETCH). Block = 128 (2 waves = 2 o's), grid
// (N/NC, O/2, B). lane = d (coalesced H load / out store); n wave-uniform ->
// Psp row arrives via s_load as the scalar operand of v_fmac.
// H/Psp re-read per o-pair is served by L2/L3 (16 MB << 256 MB L3).
__global__ __launch_bounds__(128) void k_main(const float* __restrict__ H,
                                              const float* __restrict__ alpha,
                                              const float* __restrict__ ws,
                                              float* __restrict__ out) {
    const float* __restrict__ Psp = ws + OFF_PSP;
    const float* __restrict__ SUa = ws + OFF_SUA;
    int b = blockIdx.z;
    int o = blockIdx.y * 2 + (threadIdx.x >> 6);
    int nbase = blockIdx.x * NC_;
    int lane = threadIdx.x & 63;
    float a = fminf(fmaxf(alpha[0], 0.0f), 1.0f);
    float oma = 1.0f - a;

    // This wave's o-slice of a*s*U: su[r] (32 VGPRs)
    float su[R_];
    const float* sp = SUa + ((size_t)(b * O_ + o) * R_) * D_ + lane;
    #pragma unroll
    for (int r = 0; r < R_; ++r) su[r] = sp[r * D_];

    const float* __restrict__ Hb = H + ((size_t)b * N_ + nbase) * D_ + lane;
    float* __restrict__ op = out + ((size_t)(b * O_ + o) * N_ + nbase) * D_ + lane;

    float hv = Hb[0];
    for (int ni = 0; ni < NC_; ++ni) {
        // Prefetch next H row (clamped at chunk end) so the global load
        // overlaps this iteration's FMA chain.
        int nin = (ni + 1 < NC_) ? ni + 1 : ni;
        float hvn = Hb[nin * D_];
        const float* pp = Psp + (size_t)(nbase + ni) * R_;  // uniform -> s_load
        float acc = oma * hv;
        #pragma unroll
        for (int r = 0; r < R_; ++r) acc = fmaf(pp[r], su[r], acc);
        op[ni * D_] = acc;
        hv = hvn;
    }
}

extern "C" void kernel_launch(void* const* d_in, const int* in_sizes, int n_in,
                              void* d_out, int out_size, void* d_ws, size_t ws_size,
                              hipStream_t stream) {
    const float* H      = (const float*)d_in[0];
    const float* ts_out = (const float*)d_in[1];
    // d_in[2] is O (int scalar) — shapes are compile-time constants here
    const float* P_raw  = (const float*)d_in[3];
    const float* Q_raw  = (const float*)d_in[4];
    const float* W1     = (const float*)d_in[5];
    const float* b1     = (const float*)d_in[6];
    const float* W2     = (const float*)d_in[7];
    const float* b2     = (const float*)d_in[8];
    const float* alpha  = (const float*)d_in[9];
    float* out = (float*)d_out;
    float* ws  = (float*)d_ws;

    // 1. softplus of Q_raw and P_raw
    k_softplus<<<dim3((2 * N_ * R_ + 255) / 256), dim3(256), 0, stream>>>(Q_raw, P_raw, ws);
    // 2a. partial U
    k_upart<<<dim3(B_ * NCH_), dim3(512), 0, stream>>>(H, ws);
    // 2b. reduce U + ctx
    k_ured<<<dim3(B_), dim3(512), 0, stream>>>(ws);
    // 3. MLP -> s -> SUa
    k_mlp<<<dim3(B_ * O_), dim3(128), 0, stream>>>(ts_out, W1, b1, W2, b2, alpha, ws);
    // 4. main fused output: one o per wave, 2 waves/block
    k_main<<<dim3(N_ / NC_, O_ / 2, B_), dim3(128), 0, stream>>>(H, alpha, ws, out);
}

// Round 4
// 107.585 us; speedup vs baseline: 5.6880x; 1.0503x over previous
//
#include <hip/hip_runtime.h>
#include <math.h>

// Problem constants (fixed by the reference setup)
#define B_ 32
#define N_ 2048
#define D_ 64
#define R_ 32
#define T_ 31
#define O_ 12
#define HID_ 128
#define IN_DIM_ 63      // T_ + R_
#define NCH_ 32         // n-chunks for partial-U reduction (32 -> 1024 blocks, 8 waves/SIMD)
#define NC_ 64          // n rows per block in main kernel

// Workspace layout (float offsets)
#define OFF_QSP   0
#define OFF_PSP   (N_*R_)                        // 65536
#define OFF_UPART (OFF_PSP + N_*R_)              // 131072
#define OFF_U     (OFF_UPART + B_*NCH_*R_*D_)    // 131072 + 2097152
#define OFF_CTX   (OFF_U + B_*R_*D_)
#define OFF_SUA   (OFF_CTX + B_*R_)
// total floats ~ 3.1M (~12 MB) — well under ws

__device__ __forceinline__ float softplus_f(float x) {
    return fmaxf(x, 0.0f) + log1pf(expf(-fabsf(x)));
}
__device__ __forceinline__ float gelu_f(float x) {
    return 0.5f * x * (1.0f + erff(x * 0.70710678118654752440f));
}

// Kernel 1: softplus(Q_raw) -> Qsp, softplus(P_raw) -> Psp
__global__ __launch_bounds__(256) void k_softplus(const float* __restrict__ Qr,
                                                  const float* __restrict__ Pr,
                                                  float* __restrict__ ws) {
    int i = blockIdx.x * blockDim.x + threadIdx.x;
    if (i < N_ * R_) {
        ws[OFF_QSP + i] = softplus_f(Qr[i]);
    } else if (i < 2 * N_ * R_) {
        int j = i - N_ * R_;
        ws[OFF_PSP + j] = softplus_f(Pr[j]);
    }
}

// Kernel 2a: partial U over n-chunks. grid = B_*NCH_ = 1024 blocks, 512 threads
// (8 waves/SIMD). thread: d = tid&63, wave-group rb = tid>>6 owns r in
// [rb*4, rb*4+4) -> CONTIGUOUS r => Q row slice is one s_load_dwordx4.
__global__ __launch_bounds__(512) void k_upart(const float* __restrict__ H,
                                               float* __restrict__ ws) {
    const float* __restrict__ Qsp = ws + OFF_QSP;
    float* __restrict__ Upart = ws + OFF_UPART;
    int b = blockIdx.x / NCH_;
    int c = blockIdx.x % NCH_;
    int tid = threadIdx.x;
    int d = tid & 63;
    int rb = __builtin_amdgcn_readfirstlane(tid >> 6);  // 0..7, wave-uniform
    const int r0 = rb * 4;
    float acc0 = 0.f, acc1 = 0.f, acc2 = 0.f, acc3 = 0.f;
    const int n0 = c * (N_ / NCH_);   // 64 rows per chunk
    const float* __restrict__ Hb = H + (size_t)b * N_ * D_ + d;
    #pragma unroll 2
    for (int i = 0; i < N_ / NCH_; ++i) {
        int n = n0 + i;
        float h = Hb[(size_t)n * D_];
        const float* q = Qsp + (size_t)n * R_ + r0;   // uniform -> s_load_dwordx4
        acc0 = fmaf(h, q[0], acc0);
        acc1 = fmaf(h, q[1], acc1);
        acc2 = fmaf(h, q[2], acc2);
        acc3 = fmaf(h, q[3], acc3);
    }
    float* up = Upart + ((size_t)(b * NCH_ + c) * R_ + r0) * D_ + d;
    up[0 * D_] = acc0;
    up[1 * D_] = acc1;
    up[2 * D_] = acc2;
    up[3 * D_] = acc3;
}

// Kernel 2b: reduce partials -> U, compute ctx = sqrt(mean_d U^2 + eps)
__global__ __launch_bounds__(512) void k_ured(float* __restrict__ ws) {
    const float* __restrict__ Upart = ws + OFF_UPART;
    float* __restrict__ U = ws + OFF_U;
    float* __restrict__ ctx = ws + OFF_CTX;
    int b = blockIdx.x;
    int tid = threadIdx.x;
    int d = tid & 63;
    int rb = tid >> 6;
    #pragma unroll
    for (int j = 0; j < 4; ++j) {
        int r = rb * 4 + j;
        float u = 0.f;
        #pragma unroll 8
        for (int c = 0; c < NCH_; ++c)
            u += Upart[((size_t)(b * NCH_ + c) * R_ + r) * D_ + d];
        U[((size_t)b * R_ + r) * D_ + d] = u;
        float sq = u * u;
        #pragma unroll
        for (int off = 32; off; off >>= 1) sq += __shfl_xor(sq, off, 64);
        if (d == 0) ctx[b * R_ + r] = sqrtf(sq * (1.0f / D_) + 1e-6f);
    }
}

// Kernel 3: per (b,o): feat -> gelu(feat@W1+b1) -> softplus(h@W2+b2)=s,
// then SUa[b,o,r,d] = a * s[r] * U[b,r,d].  grid = B_*O_, 128 threads.
__global__ __launch_bounds__(128) void k_mlp(const float* __restrict__ ts_out,
                                             const float* __restrict__ W1,
                                             const float* __restrict__ b1,
                                             const float* __restrict__ W2,
                                             const float* __restrict__ b2,
                                             const float* __restrict__ alpha,
                                             float* __restrict__ ws) {
    __shared__ float feat[IN_DIM_];
    __shared__ float hsh[HID_];
    __shared__ float ssh[R_];
    int bo = blockIdx.x;
    int b = bo / O_;
    int tid = threadIdx.x;
    const float* __restrict__ ctx = ws + OFF_CTX;
    if (tid < T_) feat[tid] = ts_out[(size_t)bo * T_ + tid];
    else if (tid < IN_DIM_) feat[tid] = ctx[b * R_ + (tid - T_)];
    __syncthreads();
    float acc = b1[tid];
    #pragma unroll 9
    for (int k = 0; k < IN_DIM_; ++k) acc = fmaf(feat[k], W1[k * HID_ + tid], acc);
    hsh[tid] = gelu_f(acc);
    __syncthreads();
    if (tid < R_) {
        float a2 = b2[tid];
        #pragma unroll 8
        for (int j = 0; j < HID_; ++j) a2 = fmaf(hsh[j], W2[j * R_ + tid], a2);
        ssh[tid] = softplus_f(a2);
    }
    __syncthreads();
    float a = fminf(fmaxf(alpha[0], 0.0f), 1.0f);
    const float* __restrict__ U = ws + OFF_U;
    float* __restrict__ SUa = ws + OFF_SUA;
    #pragma unroll
    for (int idx = tid; idx < R_ * D_; idx += 128) {
        int r = idx >> 6, d = idx & 63;
        SUa[((size_t)bo * R_ + r) * D_ + d] = a * ssh[r] * U[((size_t)b * R_ + r) * D_ + d];
    }
}

// Kernel 4: out[b,o,n,d] = (1-a)*H[b,n,d] + sum_r Psp[n,r]*SUa[b,o,r,d]
// One o per wave (su[32] = 32 VGPR; no launch_bounds cap — R2 lesson).
// n unrolled x2: two independent accumulator chains, two H loads and two
// P-row s_loads in flight per iteration (R3's single chain was 32 dependent
// fmac ~128cy serial per store).
__global__ __launch_bounds__(128) void k_main(const float* __restrict__ H,
                                              const float* __restrict__ alpha,
                                              const float* __restrict__ ws,
                                              float* __restrict__ out) {
    const float* __restrict__ Psp = ws + OFF_PSP;
    const float* __restrict__ SUa = ws + OFF_SUA;
    int b = blockIdx.z;
    int o = blockIdx.y * 2 + (threadIdx.x >> 6);
    int nbase = blockIdx.x * NC_;
    int lane = threadIdx.x & 63;
    float a = fminf(fmaxf(alpha[0], 0.0f), 1.0f);
    float oma = 1.0f - a;

    // This wave's o-slice of a*s*U: su[r] (32 VGPRs)
    float su[R_];
    const float* sp = SUa + ((size_t)(b * O_ + o) * R_) * D_ + lane;
    #pragma unroll
    for (int r = 0; r < R_; ++r) su[r] = sp[r * D_];

    const float* __restrict__ Hb = H + ((size_t)b * N_ + nbase) * D_ + lane;
    float* __restrict__ op = out + ((size_t)(b * O_ + o) * N_ + nbase) * D_ + lane;

    for (int ni = 0; ni < NC_; ni += 2) {
        float hv0 = Hb[(size_t)ni * D_];
        float hv1 = Hb[(size_t)ni * D_ + D_];
        const float* pp = Psp + (size_t)(nbase + ni) * R_;  // uniform -> s_load x2 rows
        float acc0 = oma * hv0;
        float acc1 = oma * hv1;
        #pragma unroll
        for (int r = 0; r < R_; ++r) {
            acc0 = fmaf(pp[r],      su[r], acc0);
            acc1 = fmaf(pp[R_ + r], su[r], acc1);
        }
        op[(size_t)ni * D_]      = acc0;
        op[(size_t)ni * D_ + D_] = acc1;
    }
}

extern "C" void kernel_launch(void* const* d_in, const int* in_sizes, int n_in,
                              void* d_out, int out_size, void* d_ws, size_t ws_size,
                              hipStream_t stream) {
    const float* H      = (const float*)d_in[0];
    const float* ts_out = (const float*)d_in[1];
    // d_in[2] is O (int scalar) — shapes are compile-time constants here
    const float* P_raw  = (const float*)d_in[3];
    const float* Q_raw  = (const float*)d_in[4];
    const float* W1     = (const float*)d_in[5];
    const float* b1     = (const float*)d_in[6];
    const float* W2     = (const float*)d_in[7];
    const float* b2     = (const float*)d_in[8];
    const float* alpha  = (const float*)d_in[9];
    float* out = (float*)d_out;
    float* ws  = (float*)d_ws;

    // 1. softplus of Q_raw and P_raw
    k_softplus<<<dim3((2 * N_ * R_ + 255) / 256), dim3(256), 0, stream>>>(Q_raw, P_raw, ws);
    // 2a. partial U (1024 blocks -> 8 waves/SIMD)
    k_upart<<<dim3(B_ * NCH_), dim3(512), 0, stream>>>(H, ws);
    // 2b. reduce U + ctx
    k_ured<<<dim3(B_), dim3(512), 0, stream>>>(ws);
    // 3. MLP -> s -> SUa
    k_mlp<<<dim3(B_ * O_), dim3(128), 0, stream>>>(ts_out, W1, b1, W2, b2, alpha, ws);
    // 4. main fused output: one o per wave, 2 waves/block, n unrolled x2
    k_main<<<dim3(N_ / NC_, O_ / 2, B_), dim3(128), 0, stream>>>(H, alpha, ws, out);
}

// Round 5
// 80.501 us; speedup vs baseline: 7.6017x; 1.3364x over previous
//
#include <hip/hip_runtime.h>
#include <math.h>

// Problem constants (fixed by the reference setup)
#define B_ 32
#define N_ 2048
#define D_ 64
#define R_ 32
#define T_ 31
#define O_ 12
#define HID_ 128
#define IN_DIM_ 63      // T_ + R_
#define NCH_ 32         // n-chunks for partial-U reduction

// Workspace layout (float offsets)
#define OFF_QSP   0
#define OFF_UPART (OFF_QSP + N_*R_)              // 65536
#define OFF_U     (OFF_UPART + B_*NCH_*R_*D_)    // 2162688
#define OFF_CTX   (OFF_U + B_*R_*D_)             // 2228224
#define OFF_PBF   (OFF_CTX + B_*R_)              // 2229248 (bf16 area, ushort*)
#define OFF_SUT   (OFF_PBF + N_*R_/2)            // 2262016 (bf16 area, ushort*)
// end = OFF_SUT + B_*O_*D_*R_/2 = 2,655,232 floats = 10.6 MB (< ws)

typedef __attribute__((ext_vector_type(4))) float f32x4;
typedef __attribute__((ext_vector_type(8))) short short8;

__device__ __forceinline__ float softplus_f(float x) {
    return fmaxf(x, 0.0f) + log1pf(expf(-fabsf(x)));
}
__device__ __forceinline__ float gelu_f(float x) {
    return 0.5f * x * (1.0f + erff(x * 0.70710678118654752440f));
}
// float -> bf16 bits, round-to-nearest-even (inputs are finite positives here)
__device__ __forceinline__ unsigned short f2bf(float f) {
    unsigned int u = __float_as_uint(f);
    u = (u + 0x7FFFu + ((u >> 16) & 1u)) >> 16;
    return (unsigned short)u;
}

// Kernel 1: Qsp = softplus(Q_raw) fp32 (for k_upart); Pbf = bf16(softplus(P_raw))
__global__ __launch_bounds__(256) void k_softplus(const float* __restrict__ Qr,
                                                  const float* __restrict__ Pr,
                                                  float* __restrict__ ws) {
    int i = blockIdx.x * blockDim.x + threadIdx.x;
    if (i < N_ * R_) {
        ws[OFF_QSP + i] = softplus_f(Qr[i]);
    } else if (i < 2 * N_ * R_) {
        int j = i - N_ * R_;
        ((unsigned short*)(ws + OFF_PBF))[j] = f2bf(softplus_f(Pr[j]));
    }
}

// Kernel 2a: partial U over n-chunks. grid = B_*NCH_ = 1024 blocks, 512 threads.
__global__ __launch_bounds__(512) void k_upart(const float* __restrict__ H,
                                               float* __restrict__ ws) {
    const float* __restrict__ Qsp = ws + OFF_QSP;
    float* __restrict__ Upart = ws + OFF_UPART;
    int b = blockIdx.x / NCH_;
    int c = blockIdx.x % NCH_;
    int tid = threadIdx.x;
    int d = tid & 63;
    int rb = __builtin_amdgcn_readfirstlane(tid >> 6);  // 0..7, wave-uniform
    const int r0 = rb * 4;
    float acc0 = 0.f, acc1 = 0.f, acc2 = 0.f, acc3 = 0.f;
    const int n0 = c * (N_ / NCH_);   // 64 rows per chunk
    const float* __restrict__ Hb = H + (size_t)b * N_ * D_ + d;
    #pragma unroll 2
    for (int i = 0; i < N_ / NCH_; ++i) {
        int n = n0 + i;
        float h = Hb[(size_t)n * D_];
        const float* q = Qsp + (size_t)n * R_ + r0;   // uniform -> s_load_dwordx4
        acc0 = fmaf(h, q[0], acc0);
        acc1 = fmaf(h, q[1], acc1);
        acc2 = fmaf(h, q[2], acc2);
        acc3 = fmaf(h, q[3], acc3);
    }
    float* up = Upart + ((size_t)(b * NCH_ + c) * R_ + r0) * D_ + d;
    up[0 * D_] = acc0;
    up[1 * D_] = acc1;
    up[2 * D_] = acc2;
    up[3 * D_] = acc3;
}

// Kernel 2b: reduce partials -> U, ctx = sqrt(mean_d U^2 + eps)
__global__ __launch_bounds__(512) void k_ured(float* __restrict__ ws) {
    const float* __restrict__ Upart = ws + OFF_UPART;
    float* __restrict__ U = ws + OFF_U;
    float* __restrict__ ctx = ws + OFF_CTX;
    int b = blockIdx.x;
    int tid = threadIdx.x;
    int d = tid & 63;
    int rb = tid >> 6;
    #pragma unroll
    for (int j = 0; j < 4; ++j) {
        int r = rb * 4 + j;
        float u = 0.f;
        #pragma unroll 8
        for (int c = 0; c < NCH_; ++c)
            u += Upart[((size_t)(b * NCH_ + c) * R_ + r) * D_ + d];
        U[((size_t)b * R_ + r) * D_ + d] = u;
        float sq = u * u;
        #pragma unroll
        for (int off = 32; off; off >>= 1) sq += __shfl_xor(sq, off, 64);
        if (d == 0) ctx[b * R_ + r] = sqrtf(sq * (1.0f / D_) + 1e-6f);
    }
}

// Kernel 3: MLP -> s, then SUT[b,o][d][r] = bf16(a * s[r] * U[b,r,d])  (B-operand,
// transposed so 8 consecutive r per lane = one 16B load). grid B_*O_, 128 thr.
__global__ __launch_bounds__(128) void k_mlp(const float* __restrict__ ts_out,
                                             const float* __restrict__ W1,
                                             const float* __restrict__ b1,
                                             const float* __restrict__ W2,
                                             const float* __restrict__ b2,
                                             const float* __restrict__ alpha,
                                             float* __restrict__ ws) {
    __shared__ float feat[IN_DIM_];
    __shared__ float hsh[HID_];
    __shared__ float ssh[R_];
    int bo = blockIdx.x;
    int b = bo / O_;
    int tid = threadIdx.x;
    const float* __restrict__ ctx = ws + OFF_CTX;
    if (tid < T_) feat[tid] = ts_out[(size_t)bo * T_ + tid];
    else if (tid < IN_DIM_) feat[tid] = ctx[b * R_ + (tid - T_)];
    __syncthreads();
    float acc = b1[tid];
    #pragma unroll 9
    for (int k = 0; k < IN_DIM_; ++k) acc = fmaf(feat[k], W1[k * HID_ + tid], acc);
    hsh[tid] = gelu_f(acc);
    __syncthreads();
    if (tid < R_) {
        float a2 = b2[tid];
        #pragma unroll 8
        for (int j = 0; j < HID_; ++j) a2 = fmaf(hsh[j], W2[j * R_ + tid], a2);
        ssh[tid] = softplus_f(a2);
    }
    __syncthreads();
    float a = fminf(fmaxf(alpha[0], 0.0f), 1.0f);
    const float* __restrict__ U = ws + OFF_U;
    unsigned short* SUT = (unsigned short*)(ws + OFF_SUT) + (size_t)bo * D_ * R_;
    #pragma unroll
    for (int idx = tid; idx < D_ * R_; idx += 128) {
        int d = idx >> 5, r = idx & 31;
        SUT[idx] = f2bf(a * ssh[r] * U[((size_t)b * R_ + r) * D_ + d]);
    }
}

// Kernel 4 (MFMA): per b, 64-n tile: out[b,o,n,d] = oma*H[b,n,d] + P[n,:]@SUT[b,o][:,d]
// One mfma_f32_16x16x32_bf16 per 16n x 16d tile (K=32 in one shot).
// A-frag: lane l -> A[m=l&15][k=(l>>4)*8+j] = Pbf row-major, 16B coalesced.
// B-frag: lane l -> B[k=(l>>4)*8+j][n=l&15] = SUT[d][r] row-major, 16B coalesced.
// C/D:    lane l -> D[row=(l>>4)*4+j][col=l&15]  (verified m89/m91 layout).
// grid (N/64, B), block 256 (4 waves; wave w owns rows n0=blk*64+w*16, all d, all o).
__global__ __launch_bounds__(256) void k_main(const float* __restrict__ H,
                                              const float* __restrict__ alpha,
                                              const float* __restrict__ ws,
                                              float* __restrict__ out) {
    const int b = blockIdx.y;
    const int n0 = blockIdx.x * 64 + (threadIdx.x >> 6) * 16;
    const int lane = threadIdx.x & 63;
    const int l16 = lane & 15;
    const int lhi = lane >> 4;
    const float a = fminf(fmaxf(alpha[0], 0.0f), 1.0f);
    const float oma = 1.0f - a;

    const unsigned short* Pbf = (const unsigned short*)(ws + OFF_PBF);
    const unsigned short* SUT0 = (const unsigned short*)(ws + OFF_SUT);

    // A fragment: P rows n0+l16, k-slice lhi*8..+8 (shared across all o)
    short8 afrag = *(const short8*)(Pbf + (size_t)(n0 + l16) * R_ + lhi * 8);

    // H tile, pre-scaled: homa[db*4+j] = oma * H[n0 + lhi*4 + j][db*16 + l16]
    const float* __restrict__ Hb = H + ((size_t)b * N_ + n0) * D_;
    float homa[16];
    #pragma unroll
    for (int db = 0; db < 4; ++db)
        #pragma unroll
        for (int j = 0; j < 4; ++j)
            homa[db * 4 + j] = oma * Hb[(size_t)(lhi * 4 + j) * D_ + db * 16 + l16];

    float* __restrict__ op0 = out + ((size_t)(b * O_) * N_ + n0) * D_;

    for (int o = 0; o < O_; ++o) {
        const unsigned short* SUT = SUT0 + (size_t)(b * O_ + o) * D_ * R_;
        f32x4 acc[4];
        #pragma unroll
        for (int db = 0; db < 4; ++db) {
            short8 bfrag = *(const short8*)(SUT + (size_t)(db * 16 + l16) * R_ + lhi * 8);
            acc[db] = __builtin_amdgcn_mfma_f32_16x16x32_bf16(
                afrag, bfrag, (f32x4){0.f, 0.f, 0.f, 0.f}, 0, 0, 0);
        }
        float* __restrict__ op = op0 + (size_t)o * N_ * D_;
        #pragma unroll
        for (int db = 0; db < 4; ++db)
            #pragma unroll
            for (int j = 0; j < 4; ++j)
                op[(size_t)(lhi * 4 + j) * D_ + db * 16 + l16] = homa[db * 4 + j] + acc[db][j];
    }
}

extern "C" void kernel_launch(void* const* d_in, const int* in_sizes, int n_in,
                              void* d_out, int out_size, void* d_ws, size_t ws_size,
                              hipStream_t stream) {
    const float* H      = (const float*)d_in[0];
    const float* ts_out = (const float*)d_in[1];
    // d_in[2] is O (int scalar) — shapes are compile-time constants here
    const float* P_raw  = (const float*)d_in[3];
    const float* Q_raw  = (const float*)d_in[4];
    const float* W1     = (const float*)d_in[5];
    const float* b1     = (const float*)d_in[6];
    const float* W2     = (const float*)d_in[7];
    const float* b2     = (const float*)d_in[8];
    const float* alpha  = (const float*)d_in[9];
    float* out = (float*)d_out;
    float* ws  = (float*)d_ws;

    // 1. softplus: Qsp fp32 + Pbf bf16
    k_softplus<<<dim3((2 * N_ * R_ + 255) / 256), dim3(256), 0, stream>>>(Q_raw, P_raw, ws);
    // 2a. partial U (1024 blocks -> 8 waves/SIMD)
    k_upart<<<dim3(B_ * NCH_), dim3(512), 0, stream>>>(H, ws);
    // 2b. reduce U + ctx
    k_ured<<<dim3(B_), dim3(512), 0, stream>>>(ws);
    // 3. MLP -> s -> SUT (bf16, [d][r])
    k_mlp<<<dim3(B_ * O_), dim3(128), 0, stream>>>(ts_out, W1, b1, W2, b2, alpha, ws);
    // 4. main fused output via MFMA
    k_main<<<dim3(N_ / 64, B_), dim3(256), 0, stream>>>(H, alpha, ws, out);
}